// Round 2
// 310.581 us; speedup vs baseline: 1.0817x; 1.0817x over previous
//
#include <hip/hip_runtime.h>

#define EPSN 1e-3f

typedef __attribute__((ext_vector_type(8))) short short8;
typedef __attribute__((ext_vector_type(4))) float floatx4;

__device__ __forceinline__ unsigned f2bf_pack(float a, float b) {
    unsigned ua = __builtin_bit_cast(unsigned, a);
    ua += 0x7FFF + ((ua >> 16) & 1);
    unsigned ub = __builtin_bit_cast(unsigned, b);
    ub += 0x7FFF + ((ub >> 16) & 1);
    return (ua >> 16) | (ub & 0xFFFF0000u);
}
__device__ __forceinline__ unsigned short f2bf(float f) {
    unsigned u = __builtin_bit_cast(unsigned, f);
    u += 0x7FFF + ((u >> 16) & 1);
    return (unsigned short)(u >> 16);
}
__device__ __forceinline__ float bf2f(unsigned short u) {
    unsigned v = ((unsigned)u) << 16;
    return __builtin_bit_cast(float, v);
}

// ---------------- Kernel 0: weights fp32 -> bf16 MFMA B-frag layout ----------
// Wgh: n in [0,128) (0..63 = w_f, 64..127 = w_h), k in [0,512).
//   Wgh[((ntile*64 + k8)*16 + n16)*8 + j] = W[k8*8+j][ntile*16+n16]
// Wf3: n in [0,512), k in [0,64).
//   Wf3[((ntile*8 + k8)*16 + n16)*8 + j] = w_fgh[k8*8+j][ntile*16+n16]
__global__ void k0_convert(const float* __restrict__ w_f,
                           const float* __restrict__ w_h,
                           const float* __restrict__ w_fgh,
                           unsigned short* __restrict__ Wgh,
                           unsigned short* __restrict__ Wf3)
{
    int tid = blockIdx.x * 256 + threadIdx.x;
    if (tid < 8192) {
        int n16 = tid & 15, k8 = (tid >> 4) & 63, ntile = tid >> 10;
        int n = ntile * 16 + n16;
        const float* src = (n < 64) ? (w_f + n) : (w_h + (n - 64));
        unsigned short o[8];
        #pragma unroll
        for (int j = 0; j < 8; ++j) o[j] = f2bf(src[(size_t)(k8 * 8 + j) * 64]);
        *(uint4*)&Wgh[(size_t)tid * 8] = *(const uint4*)o;
    } else if (tid < 12288) {
        int id = tid - 8192;
        int n16 = id & 15, k8 = (id >> 4) & 7, ntile = id >> 7;
        int n = ntile * 16 + n16;
        unsigned short o[8];
        #pragma unroll
        for (int j = 0; j < 8; ++j) o[j] = f2bf(w_fgh[(size_t)(k8 * 8 + j) * 512 + n]);
        *(uint4*)&Wf3[(size_t)id * 8] = *(const uint4*)o;
    }
}

// ---------------- Kernel 1: x @ (w_f|w_h) + fused LN -> g (fp32), h (bf16) ---
// Zero LDS, zero barriers. Block 256 (4 waves), 64 rows/block, 16 rows/wave.
// Retiled from 128 rows/block: grid 512 -> 1024 (4 blocks/CU, 16 waves/CU),
// acc halved to 32 regs so __launch_bounds__(256,4) fits, K-loop fully
// unrolled with explicit next-iteration x prefetch -> deeper VMEM pipeline.
__global__ __launch_bounds__(256, 4) void k1_gemm_ln(
    const float* __restrict__ x,
    const unsigned short* __restrict__ Wgh,
    const float* __restrict__ gamma_f, const float* __restrict__ beta_f,
    const float* __restrict__ gamma_h, const float* __restrict__ beta_h,
    float* __restrict__ g_out, unsigned short* __restrict__ h_out)
{
    const int t = threadIdx.x;
    const int lane = t & 63;
    const int wv = t >> 6;
    const int quad = lane >> 4;
    const int n16 = lane & 15;
    const int row_base = blockIdx.x * 64 + wv * 16;

    floatx4 acc[8];
    #pragma unroll
    for (int ct = 0; ct < 8; ++ct) acc[ct] = (floatx4){0.f, 0.f, 0.f, 0.f};

    const float* xrow = x + (size_t)(row_base + n16) * 512 + quad * 8;

    // Prefetch c=0's x chunk.
    float4 u = *(const float4*)(xrow);
    float4 v = *(const float4*)(xrow + 4);

    #pragma unroll
    for (int c = 0; c < 16; ++c) {
        float4 un = u, vn = v;
        if (c < 15) {
            un = *(const float4*)(xrow + (c + 1) * 32);
            vn = *(const float4*)(xrow + (c + 1) * 32 + 4);
        }
        union { short8 s; uint4 q; } cvt;
        cvt.q = make_uint4(f2bf_pack(u.x, u.y), f2bf_pack(u.z, u.w),
                           f2bf_pack(v.x, v.y), f2bf_pack(v.z, v.w));
        short8 a = cvt.s;
        #pragma unroll
        for (int ct = 0; ct < 8; ++ct) {
            short8 b = *(const short8*)&Wgh[(size_t)(((ct * 64) + c * 4 + quad) * 16 + n16) * 8];
            acc[ct] = __builtin_amdgcn_mfma_f32_16x16x32_bf16(a, b, acc[ct], 0, 0, 0);
        }
        u = un; v = vn;
    }

    // Epilogue: per-wave in-register LN over each 64-col half.
    #pragma unroll
    for (int half = 0; half < 2; ++half) {
        float s[4] = {0.f, 0.f, 0.f, 0.f}, s2[4] = {0.f, 0.f, 0.f, 0.f};
        #pragma unroll
        for (int c0 = 0; c0 < 4; ++c0) {
            int ct = half * 4 + c0;
            #pragma unroll
            for (int r = 0; r < 4; ++r) {
                float val = acc[ct][r];
                s[r] += val; s2[r] += val * val;
            }
        }
        #pragma unroll
        for (int off = 1; off <= 8; off <<= 1)
            #pragma unroll
            for (int r = 0; r < 4; ++r) {
                s[r]  += __shfl_xor(s[r],  off, 64);
                s2[r] += __shfl_xor(s2[r], off, 64);
            }
        float mean[4], rstd[4];
        #pragma unroll
        for (int r = 0; r < 4; ++r) {
            mean[r] = s[r] * (1.f / 64.f);
            float var = s2[r] * (1.f / 64.f) - mean[r] * mean[r];
            rstd[r] = rsqrtf(var + EPSN);
        }
        #pragma unroll
        for (int c0 = 0; c0 < 4; ++c0) {
            int ct = half * 4 + c0;
            int col = c0 * 16 + n16;
            float gm = half ? gamma_h[col] : gamma_f[col];
            float bt = half ? beta_h[col]  : beta_f[col];
            #pragma unroll
            for (int r = 0; r < 4; ++r) {
                int row = row_base + quad * 4 + r;
                float val = (acc[ct][r] - mean[r]) * rstd[r] * gm + bt;
                if (half == 0)
                    g_out[(size_t)row * 64 + col] = val;
                else
                    h_out[(size_t)row * 64 + col] = f2bf(val);
            }
        }
    }
}

// ---------------- Kernel 2: softmax over H of f*g, times h -> t (bf16 row-major)
__global__ __launch_bounds__(256, 4) void k2_softmax(
    const float* __restrict__ g_in,
    const unsigned short* __restrict__ h_in,
    unsigned short* __restrict__ t_out)
{
    __shared__ float S[64 * 64];
    __shared__ float Hm[64 * 64];
    __shared__ float pmax[4 * 64];
    __shared__ float psum[4 * 64];
    __shared__ float colmax[64];
    __shared__ float colinv[64];

    const int t = threadIdx.x;
    const int b = blockIdx.x >> 6;
    const int w = blockIdx.x & 63;
    const size_t base1 = (size_t)(b * 64 + w) * 4096;

    #pragma unroll
    for (int i = 0; i < 16; ++i) {
        int e = t + i * 256;
        int hh = e >> 6, ii = e & 63;
        size_t idx2 = ((size_t)((b * 64 + hh) * 64 + w)) * 64 + ii;
        S[e]  = g_in[base1 + e] * g_in[idx2];
        Hm[e] = bf2f(h_in[idx2]);
    }
    __syncthreads();

    const int q = t >> 6;
    const int i = t & 63;
    float m = -1e30f;
    #pragma unroll
    for (int r = 0; r < 16; ++r)
        m = fmaxf(m, S[(q * 16 + r) * 64 + i]);
    pmax[q * 64 + i] = m;
    __syncthreads();
    if (t < 64)
        colmax[i] = fmaxf(fmaxf(pmax[i], pmax[64 + i]),
                          fmaxf(pmax[128 + i], pmax[192 + i]));
    __syncthreads();
    const float cm = colmax[i];
    float s = 0.f;
    #pragma unroll
    for (int r = 0; r < 16; ++r) {
        int idx = (q * 16 + r) * 64 + i;
        float e = __expf(S[idx] - cm);
        S[idx] = e;
        s += e;
    }
    psum[q * 64 + i] = s;
    __syncthreads();
    if (t < 64)
        colinv[i] = 1.f / (psum[i] + psum[64 + i] + psum[128 + i] + psum[192 + i]);
    __syncthreads();
    const float ci = colinv[i];
    #pragma unroll
    for (int r = 0; r < 16; ++r) {
        int hh = q * 16 + r;
        int idx = hh * 64 + i;
        size_t row_g = (size_t)((b * 64 + hh) * 64 + w);
        t_out[row_g * 64 + i] = f2bf(S[idx] * ci * Hm[idx]);
    }
}

// ---------------- Kernel 3: t @ w_fgh + LN + scale + residual ----------------
// Block 256 (4 waves): 2 rowtiles x 2 col-halves (256 cols/wave). B-frags from
// global Wf3. Cross-wave LN pairing via tiny LDS. Epilogue via per-wave 8KB
// bounce -> 512B-contiguous x reads and out writes.
__global__ __launch_bounds__(256, 4) void k3_gemm_ln_res(
    const unsigned short* __restrict__ tmat,
    const unsigned short* __restrict__ Wf3,
    const float* __restrict__ gamma, const float* __restrict__ beta,
    const float* __restrict__ scale,
    const float* __restrict__ x,
    float* __restrict__ out)
{
    __shared__ float bounce[4][16 * 132];   // 33.8 KB
    __shared__ float2 exch[4][16];

    const int t = threadIdx.x;
    const int lane = t & 63;
    const int wv = t >> 6;
    const int quad = lane >> 4;
    const int n16 = lane & 15;
    const int rowtile = blockIdx.x * 2 + (wv >> 1);
    const int half = wv & 1;

    const unsigned short* trow = tmat + (size_t)(rowtile * 16 + n16) * 64 + quad * 8;
    short8 a0 = *(const short8*)trow;
    short8 a1 = *(const short8*)(trow + 32);

    floatx4 acc[16];
    #pragma unroll
    for (int nt = 0; nt < 16; ++nt) acc[nt] = (floatx4){0.f, 0.f, 0.f, 0.f};
    #pragma unroll
    for (int nt = 0; nt < 16; ++nt) {
        int ngt = half * 16 + nt;
        short8 b0 = *(const short8*)&Wf3[(size_t)((ngt * 8 + quad) * 16 + n16) * 8];
        short8 b1 = *(const short8*)&Wf3[(size_t)((ngt * 8 + 4 + quad) * 16 + n16) * 8];
        acc[nt] = __builtin_amdgcn_mfma_f32_16x16x32_bf16(a0, b0, acc[nt], 0, 0, 0);
        acc[nt] = __builtin_amdgcn_mfma_f32_16x16x32_bf16(a1, b1, acc[nt], 0, 0, 0);
    }

    // Partial LN sums over this wave's 256 cols, reduce across 16 lanes.
    float s[4] = {0.f, 0.f, 0.f, 0.f}, s2[4] = {0.f, 0.f, 0.f, 0.f};
    #pragma unroll
    for (int nt = 0; nt < 16; ++nt)
        #pragma unroll
        for (int r = 0; r < 4; ++r) {
            float v = acc[nt][r];
            s[r] += v; s2[r] += v * v;
        }
    #pragma unroll
    for (int off = 1; off <= 8; off <<= 1)
        #pragma unroll
        for (int r = 0; r < 4; ++r) {
            s[r]  += __shfl_xor(s[r],  off, 64);
            s2[r] += __shfl_xor(s2[r], off, 64);
        }
    if (n16 == 0) {
        #pragma unroll
        for (int r = 0; r < 4; ++r)
            exch[wv][quad * 4 + r] = make_float2(s[r], s2[r]);
    }
    __syncthreads();
    float mean[4], rstd[4];
    #pragma unroll
    for (int r = 0; r < 4; ++r) {
        float2 o = exch[wv ^ 1][quad * 4 + r];
        float st = s[r] + o.x, st2 = s2[r] + o.y;
        mean[r] = st * (1.f / 512.f);
        float var = st2 * (1.f / 512.f) - mean[r] * mean[r];
        rstd[r] = rsqrtf(var + EPSN);
    }
    const float sc = scale[0];

    #pragma unroll
    for (int chunk = 0; chunk < 2; ++chunk) {
        __syncthreads();   // WAR vs previous chunk's reads (uniform across block)
        #pragma unroll
        for (int n0 = 0; n0 < 8; ++n0) {
            int nt = chunk * 8 + n0;
            int col = half * 256 + nt * 16 + n16;
            float gm = gamma[col], bt = beta[col];
            #pragma unroll
            for (int r = 0; r < 4; ++r)
                bounce[wv][(quad * 4 + r) * 132 + n0 * 16 + n16] =
                    sc * ((acc[nt][r] - mean[r]) * rstd[r] * gm + bt);
        }
        __syncthreads();
        #pragma unroll
        for (int pass = 0; pass < 8; ++pass) {
            int row = pass * 2 + (lane >> 5);
            int coff = (lane & 31) * 4;
            float4 v = *(const float4*)&bounce[wv][row * 132 + coff];
            size_t gidx = ((size_t)rowtile * 16 + row) * 512 + half * 256 + chunk * 128 + coff;
            float4 xv = *(const float4*)&x[gidx];
            float4 o;
            o.x = xv.x + v.x; o.y = xv.y + v.y; o.z = xv.z + v.z; o.w = xv.w + v.w;
            *(float4*)&out[gidx] = o;
        }
    }
}

extern "C" void kernel_launch(void* const* d_in, const int* in_sizes, int n_in,
                              void* d_out, int out_size, void* d_ws, size_t ws_size,
                              hipStream_t stream) {
    const float* x         = (const float*)d_in[0];
    const float* w_f       = (const float*)d_in[1];
    const float* w_h       = (const float*)d_in[2];
    const float* w_fgh     = (const float*)d_in[3];
    const float* gamma_f   = (const float*)d_in[4];
    const float* beta_f    = (const float*)d_in[5];
    const float* gamma_h   = (const float*)d_in[6];
    const float* beta_h    = (const float*)d_in[7];
    const float* gamma_fgh = (const float*)d_in[8];
    const float* beta_fgh  = (const float*)d_in[9];
    const float* scale     = (const float*)d_in[10];
    float* out = (float*)d_out;

    char* wsb = (char*)d_ws;
    float* g            = (float*)wsb;                            // 16 MB
    unsigned short* h   = (unsigned short*)(wsb + 16777216);      // 8 MB
    unsigned short* tm  = (unsigned short*)(wsb + 25165824);      // 8 MB
    unsigned short* Wgh = (unsigned short*)(wsb + 33554432);      // 128 KB
    unsigned short* Wf3 = (unsigned short*)(wsb + 33685504);      // 64 KB

    k0_convert<<<48, 256, 0, stream>>>(w_f, w_h, w_fgh, Wgh, Wf3);
    k1_gemm_ln<<<1024, 256, 0, stream>>>(x, Wgh, gamma_f, beta_f,
                                         gamma_h, beta_h, g, h);
    k2_softmax<<<1024, 256, 0, stream>>>(g, h, tm);
    k3_gemm_ln_res<<<2048, 256, 0, stream>>>(tm, Wf3, gamma_fgh, beta_fgh,
                                             scale, x, out);
}

// Round 3
// 309.109 us; speedup vs baseline: 1.0869x; 1.0048x over previous
//
#include <hip/hip_runtime.h>

#define EPSN 1e-3f

typedef __attribute__((ext_vector_type(8))) short short8;
typedef __attribute__((ext_vector_type(4))) float floatx4;

__device__ __forceinline__ unsigned f2bf_pack(float a, float b) {
    unsigned ua = __builtin_bit_cast(unsigned, a);
    ua += 0x7FFF + ((ua >> 16) & 1);
    unsigned ub = __builtin_bit_cast(unsigned, b);
    ub += 0x7FFF + ((ub >> 16) & 1);
    return (ua >> 16) | (ub & 0xFFFF0000u);
}
__device__ __forceinline__ unsigned short f2bf(float f) {
    unsigned u = __builtin_bit_cast(unsigned, f);
    u += 0x7FFF + ((u >> 16) & 1);
    return (unsigned short)(u >> 16);
}
__device__ __forceinline__ float bf2f(unsigned short u) {
    unsigned v = ((unsigned)u) << 16;
    return __builtin_bit_cast(float, v);
}

// ---------------- Kernel 0: weights fp32 -> bf16 MFMA B-frag layout ----------
// Wgh: n in [0,128) (0..63 = w_f, 64..127 = w_h), k in [0,512).
//   Wgh[((ntile*64 + k8)*16 + n16)*8 + j] = W[k8*8+j][ntile*16+n16]
// Wf3: n in [0,512), k in [0,64).
//   Wf3[((ntile*8 + k8)*16 + n16)*8 + j] = w_fgh[k8*8+j][ntile*16+n16]
__global__ void k0_convert(const float* __restrict__ w_f,
                           const float* __restrict__ w_h,
                           const float* __restrict__ w_fgh,
                           unsigned short* __restrict__ Wgh,
                           unsigned short* __restrict__ Wf3)
{
    int tid = blockIdx.x * 256 + threadIdx.x;
    if (tid < 8192) {
        int n16 = tid & 15, k8 = (tid >> 4) & 63, ntile = tid >> 10;
        int n = ntile * 16 + n16;
        const float* src = (n < 64) ? (w_f + n) : (w_h + (n - 64));
        unsigned short o[8];
        #pragma unroll
        for (int j = 0; j < 8; ++j) o[j] = f2bf(src[(size_t)(k8 * 8 + j) * 64]);
        *(uint4*)&Wgh[(size_t)tid * 8] = *(const uint4*)o;
    } else if (tid < 12288) {
        int id = tid - 8192;
        int n16 = id & 15, k8 = (id >> 4) & 7, ntile = id >> 7;
        int n = ntile * 16 + n16;
        unsigned short o[8];
        #pragma unroll
        for (int j = 0; j < 8; ++j) o[j] = f2bf(w_fgh[(size_t)(k8 * 8 + j) * 512 + n]);
        *(uint4*)&Wf3[(size_t)id * 8] = *(const uint4*)o;
    }
}

// ---------------- Kernel 1: x @ (w_f|w_h) + fused LN -> g (fp32), h (bf16) ---
// Zero LDS, zero barriers. Block 256 (4 waves), 64 rows/block, 16 rows/wave,
// grid 1024 (4 blocks/CU, 16 waves/CU). B-frags explicitly double-buffered in
// registers (8 loads for c+1 issued before c's MFMAs) and x prefetched 2 deep:
// the B path (L2, ~300cy) and x path (HBM, ~900cy) each stay covered instead
// of serializing through a minimal register allocation.
__global__ __launch_bounds__(256, 4) void k1_gemm_ln(
    const float* __restrict__ x,
    const unsigned short* __restrict__ Wgh,
    const float* __restrict__ gamma_f, const float* __restrict__ beta_f,
    const float* __restrict__ gamma_h, const float* __restrict__ beta_h,
    float* __restrict__ g_out, unsigned short* __restrict__ h_out)
{
    const int t = threadIdx.x;
    const int lane = t & 63;
    const int wv = t >> 6;
    const int quad = lane >> 4;
    const int n16 = lane & 15;
    const int row_base = blockIdx.x * 64 + wv * 16;

    floatx4 acc[8];
    #pragma unroll
    for (int ct = 0; ct < 8; ++ct) acc[ct] = (floatx4){0.f, 0.f, 0.f, 0.f};

    const float* xrow = x + (size_t)(row_base + n16) * 512 + quad * 8;
    // Per-thread B base: frag(c, ct) lives at boff + ct*8192 + c*512 shorts.
    const unsigned short* boff = Wgh + (size_t)(quad * 16 + n16) * 8;

    // Preload B(c=0) frags; prefetch x chunks for c=0 and c=1.
    short8 bb[8];
    #pragma unroll
    for (int ct = 0; ct < 8; ++ct)
        bb[ct] = *(const short8*)(boff + (size_t)ct * 8192);

    float4 u0 = *(const float4*)(xrow);
    float4 v0 = *(const float4*)(xrow + 4);
    float4 u1 = *(const float4*)(xrow + 32);
    float4 v1 = *(const float4*)(xrow + 36);

    #pragma unroll
    for (int c = 0; c < 16; ++c) {
        // Issue next-iteration B loads before consuming current B frags.
        short8 bn[8];
        if (c < 15) {
            #pragma unroll
            for (int ct = 0; ct < 8; ++ct)
                bn[ct] = *(const short8*)(boff + (size_t)ct * 8192 + (c + 1) * 512);
        } else {
            #pragma unroll
            for (int ct = 0; ct < 8; ++ct) bn[ct] = bb[ct];
        }
        // Issue x loads two iterations ahead (HBM stream).
        float4 u2 = u1, v2 = v1;
        if (c < 14) {
            u2 = *(const float4*)(xrow + (c + 2) * 32);
            v2 = *(const float4*)(xrow + (c + 2) * 32 + 4);
        }
        union { short8 s; uint4 q; } cvt;
        cvt.q = make_uint4(f2bf_pack(u0.x, u0.y), f2bf_pack(u0.z, u0.w),
                           f2bf_pack(v0.x, v0.y), f2bf_pack(v0.z, v0.w));
        short8 a = cvt.s;
        #pragma unroll
        for (int ct = 0; ct < 8; ++ct)
            acc[ct] = __builtin_amdgcn_mfma_f32_16x16x32_bf16(a, bb[ct], acc[ct], 0, 0, 0);
        #pragma unroll
        for (int ct = 0; ct < 8; ++ct) bb[ct] = bn[ct];
        u0 = u1; v0 = v1; u1 = u2; v1 = v2;
    }

    // Epilogue: per-wave in-register LN over each 64-col half.
    #pragma unroll
    for (int half = 0; half < 2; ++half) {
        float s[4] = {0.f, 0.f, 0.f, 0.f}, s2[4] = {0.f, 0.f, 0.f, 0.f};
        #pragma unroll
        for (int c0 = 0; c0 < 4; ++c0) {
            int ct = half * 4 + c0;
            #pragma unroll
            for (int r = 0; r < 4; ++r) {
                float val = acc[ct][r];
                s[r] += val; s2[r] += val * val;
            }
        }
        #pragma unroll
        for (int off = 1; off <= 8; off <<= 1)
            #pragma unroll
            for (int r = 0; r < 4; ++r) {
                s[r]  += __shfl_xor(s[r],  off, 64);
                s2[r] += __shfl_xor(s2[r], off, 64);
            }
        float mean[4], rstd[4];
        #pragma unroll
        for (int r = 0; r < 4; ++r) {
            mean[r] = s[r] * (1.f / 64.f);
            float var = s2[r] * (1.f / 64.f) - mean[r] * mean[r];
            rstd[r] = rsqrtf(var + EPSN);
        }
        #pragma unroll
        for (int c0 = 0; c0 < 4; ++c0) {
            int ct = half * 4 + c0;
            int col = c0 * 16 + n16;
            float gm = half ? gamma_h[col] : gamma_f[col];
            float bt = half ? beta_h[col]  : beta_f[col];
            #pragma unroll
            for (int r = 0; r < 4; ++r) {
                int row = row_base + quad * 4 + r;
                float val = (acc[ct][r] - mean[r]) * rstd[r] * gm + bt;
                if (half == 0)
                    g_out[(size_t)row * 64 + col] = val;
                else
                    h_out[(size_t)row * 64 + col] = f2bf(val);
            }
        }
    }
}

// ---------------- Kernel 2: softmax over H of f*g, times h -> t (bf16 row-major)
__global__ __launch_bounds__(256, 4) void k2_softmax(
    const float* __restrict__ g_in,
    const unsigned short* __restrict__ h_in,
    unsigned short* __restrict__ t_out)
{
    __shared__ float S[64 * 64];
    __shared__ float Hm[64 * 64];
    __shared__ float pmax[4 * 64];
    __shared__ float psum[4 * 64];
    __shared__ float colmax[64];
    __shared__ float colinv[64];

    const int t = threadIdx.x;
    const int b = blockIdx.x >> 6;
    const int w = blockIdx.x & 63;
    const size_t base1 = (size_t)(b * 64 + w) * 4096;

    #pragma unroll
    for (int i = 0; i < 16; ++i) {
        int e = t + i * 256;
        int hh = e >> 6, ii = e & 63;
        size_t idx2 = ((size_t)((b * 64 + hh) * 64 + w)) * 64 + ii;
        S[e]  = g_in[base1 + e] * g_in[idx2];
        Hm[e] = bf2f(h_in[idx2]);
    }
    __syncthreads();

    const int q = t >> 6;
    const int i = t & 63;
    float m = -1e30f;
    #pragma unroll
    for (int r = 0; r < 16; ++r)
        m = fmaxf(m, S[(q * 16 + r) * 64 + i]);
    pmax[q * 64 + i] = m;
    __syncthreads();
    if (t < 64)
        colmax[i] = fmaxf(fmaxf(pmax[i], pmax[64 + i]),
                          fmaxf(pmax[128 + i], pmax[192 + i]));
    __syncthreads();
    const float cm = colmax[i];
    float s = 0.f;
    #pragma unroll
    for (int r = 0; r < 16; ++r) {
        int idx = (q * 16 + r) * 64 + i;
        float e = __expf(S[idx] - cm);
        S[idx] = e;
        s += e;
    }
    psum[q * 64 + i] = s;
    __syncthreads();
    if (t < 64)
        colinv[i] = 1.f / (psum[i] + psum[64 + i] + psum[128 + i] + psum[192 + i]);
    __syncthreads();
    const float ci = colinv[i];
    #pragma unroll
    for (int r = 0; r < 16; ++r) {
        int hh = q * 16 + r;
        int idx = hh * 64 + i;
        size_t row_g = (size_t)((b * 64 + hh) * 64 + w);
        t_out[row_g * 64 + i] = f2bf(S[idx] * ci * Hm[idx]);
    }
}

// ---------------- Kernel 3: t @ w_fgh + LN + scale + residual ----------------
// Block 256 (4 waves): 2 rowtiles x 2 col-halves (256 cols/wave). B-frags from
// global Wf3. Cross-wave LN pairing via tiny LDS. Epilogue via per-wave 8KB
// bounce -> 512B-contiguous x reads and out writes.
__global__ __launch_bounds__(256, 4) void k3_gemm_ln_res(
    const unsigned short* __restrict__ tmat,
    const unsigned short* __restrict__ Wf3,
    const float* __restrict__ gamma, const float* __restrict__ beta,
    const float* __restrict__ scale,
    const float* __restrict__ x,
    float* __restrict__ out)
{
    __shared__ float bounce[4][16 * 132];   // 33.8 KB
    __shared__ float2 exch[4][16];

    const int t = threadIdx.x;
    const int lane = t & 63;
    const int wv = t >> 6;
    const int quad = lane >> 4;
    const int n16 = lane & 15;
    const int rowtile = blockIdx.x * 2 + (wv >> 1);
    const int half = wv & 1;

    const unsigned short* trow = tmat + (size_t)(rowtile * 16 + n16) * 64 + quad * 8;
    short8 a0 = *(const short8*)trow;
    short8 a1 = *(const short8*)(trow + 32);

    floatx4 acc[16];
    #pragma unroll
    for (int nt = 0; nt < 16; ++nt) acc[nt] = (floatx4){0.f, 0.f, 0.f, 0.f};
    #pragma unroll
    for (int nt = 0; nt < 16; ++nt) {
        int ngt = half * 16 + nt;
        short8 b0 = *(const short8*)&Wf3[(size_t)((ngt * 8 + quad) * 16 + n16) * 8];
        short8 b1 = *(const short8*)&Wf3[(size_t)((ngt * 8 + 4 + quad) * 16 + n16) * 8];
        acc[nt] = __builtin_amdgcn_mfma_f32_16x16x32_bf16(a0, b0, acc[nt], 0, 0, 0);
        acc[nt] = __builtin_amdgcn_mfma_f32_16x16x32_bf16(a1, b1, acc[nt], 0, 0, 0);
    }

    // Partial LN sums over this wave's 256 cols, reduce across 16 lanes.
    float s[4] = {0.f, 0.f, 0.f, 0.f}, s2[4] = {0.f, 0.f, 0.f, 0.f};
    #pragma unroll
    for (int nt = 0; nt < 16; ++nt)
        #pragma unroll
        for (int r = 0; r < 4; ++r) {
            float v = acc[nt][r];
            s[r] += v; s2[r] += v * v;
        }
    #pragma unroll
    for (int off = 1; off <= 8; off <<= 1)
        #pragma unroll
        for (int r = 0; r < 4; ++r) {
            s[r]  += __shfl_xor(s[r],  off, 64);
            s2[r] += __shfl_xor(s2[r], off, 64);
        }
    if (n16 == 0) {
        #pragma unroll
        for (int r = 0; r < 4; ++r)
            exch[wv][quad * 4 + r] = make_float2(s[r], s2[r]);
    }
    __syncthreads();
    float mean[4], rstd[4];
    #pragma unroll
    for (int r = 0; r < 4; ++r) {
        float2 o = exch[wv ^ 1][quad * 4 + r];
        float st = s[r] + o.x, st2 = s2[r] + o.y;
        mean[r] = st * (1.f / 512.f);
        float var = st2 * (1.f / 512.f) - mean[r] * mean[r];
        rstd[r] = rsqrtf(var + EPSN);
    }
    const float sc = scale[0];

    #pragma unroll
    for (int chunk = 0; chunk < 2; ++chunk) {
        __syncthreads();   // WAR vs previous chunk's reads (uniform across block)
        #pragma unroll
        for (int n0 = 0; n0 < 8; ++n0) {
            int nt = chunk * 8 + n0;
            int col = half * 256 + nt * 16 + n16;
            float gm = gamma[col], bt = beta[col];
            #pragma unroll
            for (int r = 0; r < 4; ++r)
                bounce[wv][(quad * 4 + r) * 132 + n0 * 16 + n16] =
                    sc * ((acc[nt][r] - mean[r]) * rstd[r] * gm + bt);
        }
        __syncthreads();
        #pragma unroll
        for (int pass = 0; pass < 8; ++pass) {
            int row = pass * 2 + (lane >> 5);
            int coff = (lane & 31) * 4;
            float4 v = *(const float4*)&bounce[wv][row * 132 + coff];
            size_t gidx = ((size_t)rowtile * 16 + row) * 512 + half * 256 + chunk * 128 + coff;
            float4 xv = *(const float4*)&x[gidx];
            float4 o;
            o.x = xv.x + v.x; o.y = xv.y + v.y; o.z = xv.z + v.z; o.w = xv.w + v.w;
            *(float4*)&out[gidx] = o;
        }
    }
}

extern "C" void kernel_launch(void* const* d_in, const int* in_sizes, int n_in,
                              void* d_out, int out_size, void* d_ws, size_t ws_size,
                              hipStream_t stream) {
    const float* x         = (const float*)d_in[0];
    const float* w_f       = (const float*)d_in[1];
    const float* w_h       = (const float*)d_in[2];
    const float* w_fgh     = (const float*)d_in[3];
    const float* gamma_f   = (const float*)d_in[4];
    const float* beta_f    = (const float*)d_in[5];
    const float* gamma_h   = (const float*)d_in[6];
    const float* beta_h    = (const float*)d_in[7];
    const float* gamma_fgh = (const float*)d_in[8];
    const float* beta_fgh  = (const float*)d_in[9];
    const float* scale     = (const float*)d_in[10];
    float* out = (float*)d_out;

    char* wsb = (char*)d_ws;
    float* g            = (float*)wsb;                            // 16 MB
    unsigned short* h   = (unsigned short*)(wsb + 16777216);      // 8 MB
    unsigned short* tm  = (unsigned short*)(wsb + 25165824);      // 8 MB
    unsigned short* Wgh = (unsigned short*)(wsb + 33554432);      // 128 KB
    unsigned short* Wf3 = (unsigned short*)(wsb + 33685504);      // 64 KB

    k0_convert<<<48, 256, 0, stream>>>(w_f, w_h, w_fgh, Wgh, Wf3);
    k1_gemm_ln<<<1024, 256, 0, stream>>>(x, Wgh, gamma_f, beta_f,
                                         gamma_h, beta_h, g, h);
    k2_softmax<<<1024, 256, 0, stream>>>(g, h, tm);
    k3_gemm_ln_res<<<2048, 256, 0, stream>>>(tm, Wf3, gamma_fgh, beta_fgh,
                                             scale, x, out);
}

// Round 4
// 297.216 us; speedup vs baseline: 1.1304x; 1.0400x over previous
//
#include <hip/hip_runtime.h>

#define EPSN 1e-3f

typedef __attribute__((ext_vector_type(8))) short short8;
typedef __attribute__((ext_vector_type(4))) float floatx4;

__device__ __forceinline__ unsigned f2bf_pack(float a, float b) {
    unsigned ua = __builtin_bit_cast(unsigned, a);
    ua += 0x7FFF + ((ua >> 16) & 1);
    unsigned ub = __builtin_bit_cast(unsigned, b);
    ub += 0x7FFF + ((ub >> 16) & 1);
    return (ua >> 16) | (ub & 0xFFFF0000u);
}
__device__ __forceinline__ unsigned short f2bf(float f) {
    unsigned u = __builtin_bit_cast(unsigned, f);
    u += 0x7FFF + ((u >> 16) & 1);
    return (unsigned short)(u >> 16);
}
__device__ __forceinline__ float bf2f(unsigned short u) {
    unsigned v = ((unsigned)u) << 16;
    return __builtin_bit_cast(float, v);
}

// Async global->LDS, 16B per lane: LDS dest = wave-uniform base + lane*16.
__device__ __forceinline__ void gload_lds16(const unsigned short* g, unsigned short* l) {
    __builtin_amdgcn_global_load_lds(
        (const __attribute__((address_space(1))) unsigned int*)g,
        (__attribute__((address_space(3))) unsigned int*)l,
        16, 0, 0);
}

// ---------------- Kernel 0: weights fp32 -> bf16 MFMA B-frag layout ----------
// Wgh: n in [0,128) (0..63 = w_f, 64..127 = w_h), k in [0,512).
//   Wgh[((ntile*64 + k8)*16 + n16)*8 + j] = W[k8*8+j][ntile*16+n16]
// Wf3: n in [0,512), k in [0,64).
//   Wf3[((ntile*8 + k8)*16 + n16)*8 + j] = w_fgh[k8*8+j][ntile*16+n16]
__global__ void k0_convert(const float* __restrict__ w_f,
                           const float* __restrict__ w_h,
                           const float* __restrict__ w_fgh,
                           unsigned short* __restrict__ Wgh,
                           unsigned short* __restrict__ Wf3)
{
    int tid = blockIdx.x * 256 + threadIdx.x;
    if (tid < 8192) {
        int n16 = tid & 15, k8 = (tid >> 4) & 63, ntile = tid >> 10;
        int n = ntile * 16 + n16;
        const float* src = (n < 64) ? (w_f + n) : (w_h + (n - 64));
        unsigned short o[8];
        #pragma unroll
        for (int j = 0; j < 8; ++j) o[j] = f2bf(src[(size_t)(k8 * 8 + j) * 64]);
        *(uint4*)&Wgh[(size_t)tid * 8] = *(const uint4*)o;
    } else if (tid < 12288) {
        int id = tid - 8192;
        int n16 = id & 15, k8 = (id >> 4) & 7, ntile = id >> 7;
        int n = ntile * 16 + n16;
        unsigned short o[8];
        #pragma unroll
        for (int j = 0; j < 8; ++j) o[j] = f2bf(w_fgh[(size_t)(k8 * 8 + j) * 512 + n]);
        *(uint4*)&Wf3[(size_t)id * 8] = *(const uint4*)o;
    }
}

// ---------------- Kernel 1: x @ (w_f|w_h) + fused LN -> g (fp32), h (bf16) ---
// Block 256 (4 waves), 64 rows/block, 16 rows/wave, grid 1024 (4 blocks/CU).
// B (Wgh) staged once per BLOCK into LDS via global_load_lds (double-buffered
// 16KB chunks of 2 K-steps), instead of every wave pulling all 128KB from L2:
// block-level B traffic /4, B off the vmcnt critical path (ds_read/lgkmcnt),
// freed VGPRs hold a 1-chunk x prefetch. 8 chunks, 1 barrier each.
__global__ __launch_bounds__(256, 4) void k1_gemm_ln(
    const float* __restrict__ x,
    const unsigned short* __restrict__ Wgh,
    const float* __restrict__ gamma_f, const float* __restrict__ beta_f,
    const float* __restrict__ gamma_h, const float* __restrict__ beta_h,
    float* __restrict__ g_out, unsigned short* __restrict__ h_out)
{
    __shared__ unsigned short Blds[2][8192];   // 2 x 16KB: [cl*8+ct]*512 shorts

    const int t = threadIdx.x;
    const int lane = t & 63;
    const int wv = t >> 6;
    const int quad = lane >> 4;
    const int n16 = lane & 15;
    const int row_base = blockIdx.x * 64 + wv * 16;

    floatx4 acc[8];
    #pragma unroll
    for (int ct = 0; ct < 8; ++ct) acc[ct] = (floatx4){0.f, 0.f, 0.f, 0.f};

    const float* xrow = x + (size_t)(row_base + n16) * 512 + quad * 8;
    // Global B frag (c, ct) slice base for this lane: + ct*8192 + c*512 shorts.
    const unsigned short* bsrc = Wgh + (size_t)lane * 8;

    // Stage chunk ch (K-steps 2ch, 2ch+1) into Blds[par]; wave wv owns slices
    // s = wv*4 .. wv*4+3, slice s = (cl = s>>3, ct = s&7), 1KB each.
    auto stage = [&](int par, int ch) {
        #pragma unroll
        for (int i = 0; i < 4; ++i) {
            int s = wv * 4 + i;
            int cl = s >> 3, ct = s & 7;
            gload_lds16(bsrc + (size_t)ct * 8192 + (ch * 2 + cl) * 512,
                        &Blds[par][s * 512]);
        }
    };

    stage(0, 0);
    float4 u[2], v[2];
    u[0] = *(const float4*)(xrow);
    v[0] = *(const float4*)(xrow + 4);
    u[1] = *(const float4*)(xrow + 32);
    v[1] = *(const float4*)(xrow + 36);
    __syncthreads();   // drains stage(0) (vmcnt) for all waves

    #pragma unroll
    for (int ch = 0; ch < 8; ++ch) {
        const int par = ch & 1;
        if (ch < 7) stage(par ^ 1, ch + 1);
        float4 un[2], vn[2];
        if (ch < 7) {
            un[0] = *(const float4*)(xrow + ch * 64 + 64);
            vn[0] = *(const float4*)(xrow + ch * 64 + 68);
            un[1] = *(const float4*)(xrow + ch * 64 + 96);
            vn[1] = *(const float4*)(xrow + ch * 64 + 100);
        }
        #pragma unroll
        for (int cl = 0; cl < 2; ++cl) {
            union { short8 s; uint4 q; } cvt;
            cvt.q = make_uint4(f2bf_pack(u[cl].x, u[cl].y), f2bf_pack(u[cl].z, u[cl].w),
                               f2bf_pack(v[cl].x, v[cl].y), f2bf_pack(v[cl].z, v[cl].w));
            short8 a = cvt.s;
            #pragma unroll
            for (int ct = 0; ct < 8; ++ct) {
                short8 b = *(const short8*)&Blds[par][(cl * 8 + ct) * 512 + lane * 8];
                acc[ct] = __builtin_amdgcn_mfma_f32_16x16x32_bf16(a, b, acc[ct], 0, 0, 0);
            }
        }
        if (ch < 7) {
            u[0] = un[0]; v[0] = vn[0]; u[1] = un[1]; v[1] = vn[1];
        }
        // One barrier per chunk: (a) all waves done reading Blds[par] before it
        // is restaged two chunks later, (b) stage into par^1 drained (vmcnt)
        // before next chunk reads it.
        __syncthreads();
    }

    // Epilogue: per-wave in-register LN over each 64-col half.
    #pragma unroll
    for (int half = 0; half < 2; ++half) {
        float s[4] = {0.f, 0.f, 0.f, 0.f}, s2[4] = {0.f, 0.f, 0.f, 0.f};
        #pragma unroll
        for (int c0 = 0; c0 < 4; ++c0) {
            int ct = half * 4 + c0;
            #pragma unroll
            for (int r = 0; r < 4; ++r) {
                float val = acc[ct][r];
                s[r] += val; s2[r] += val * val;
            }
        }
        #pragma unroll
        for (int off = 1; off <= 8; off <<= 1)
            #pragma unroll
            for (int r = 0; r < 4; ++r) {
                s[r]  += __shfl_xor(s[r],  off, 64);
                s2[r] += __shfl_xor(s2[r], off, 64);
            }
        float mean[4], rstd[4];
        #pragma unroll
        for (int r = 0; r < 4; ++r) {
            mean[r] = s[r] * (1.f / 64.f);
            float var = s2[r] * (1.f / 64.f) - mean[r] * mean[r];
            rstd[r] = rsqrtf(var + EPSN);
        }
        #pragma unroll
        for (int c0 = 0; c0 < 4; ++c0) {
            int ct = half * 4 + c0;
            int col = c0 * 16 + n16;
            float gm = half ? gamma_h[col] : gamma_f[col];
            float bt = half ? beta_h[col]  : beta_f[col];
            #pragma unroll
            for (int r = 0; r < 4; ++r) {
                int row = row_base + quad * 4 + r;
                float val = (acc[ct][r] - mean[r]) * rstd[r] * gm + bt;
                if (half == 0)
                    g_out[(size_t)row * 64 + col] = val;
                else
                    h_out[(size_t)row * 64 + col] = f2bf(val);
            }
        }
    }
}

// ---------------- Kernel 2: softmax over H of f*g, times h -> t (bf16 row-major)
__global__ __launch_bounds__(256, 4) void k2_softmax(
    const float* __restrict__ g_in,
    const unsigned short* __restrict__ h_in,
    unsigned short* __restrict__ t_out)
{
    __shared__ float S[64 * 64];
    __shared__ float Hm[64 * 64];
    __shared__ float pmax[4 * 64];
    __shared__ float psum[4 * 64];
    __shared__ float colmax[64];
    __shared__ float colinv[64];

    const int t = threadIdx.x;
    const int b = blockIdx.x >> 6;
    const int w = blockIdx.x & 63;
    const size_t base1 = (size_t)(b * 64 + w) * 4096;

    #pragma unroll
    for (int i = 0; i < 16; ++i) {
        int e = t + i * 256;
        int hh = e >> 6, ii = e & 63;
        size_t idx2 = ((size_t)((b * 64 + hh) * 64 + w)) * 64 + ii;
        S[e]  = g_in[base1 + e] * g_in[idx2];
        Hm[e] = bf2f(h_in[idx2]);
    }
    __syncthreads();

    const int q = t >> 6;
    const int i = t & 63;
    float m = -1e30f;
    #pragma unroll
    for (int r = 0; r < 16; ++r)
        m = fmaxf(m, S[(q * 16 + r) * 64 + i]);
    pmax[q * 64 + i] = m;
    __syncthreads();
    if (t < 64)
        colmax[i] = fmaxf(fmaxf(pmax[i], pmax[64 + i]),
                          fmaxf(pmax[128 + i], pmax[192 + i]));
    __syncthreads();
    const float cm = colmax[i];
    float s = 0.f;
    #pragma unroll
    for (int r = 0; r < 16; ++r) {
        int idx = (q * 16 + r) * 64 + i;
        float e = __expf(S[idx] - cm);
        S[idx] = e;
        s += e;
    }
    psum[q * 64 + i] = s;
    __syncthreads();
    if (t < 64)
        colinv[i] = 1.f / (psum[i] + psum[64 + i] + psum[128 + i] + psum[192 + i]);
    __syncthreads();
    const float ci = colinv[i];
    #pragma unroll
    for (int r = 0; r < 16; ++r) {
        int hh = q * 16 + r;
        int idx = hh * 64 + i;
        size_t row_g = (size_t)((b * 64 + hh) * 64 + w);
        t_out[row_g * 64 + i] = f2bf(S[idx] * ci * Hm[idx]);
    }
}

// ---------------- Kernel 3: t @ w_fgh + LN + scale + residual ----------------
// Block 256 (4 waves): 2 rowtiles x 2 col-halves (256 cols/wave). B-frags from
// global Wf3. Cross-wave LN pairing via tiny LDS. Epilogue via per-wave 8KB
// bounce -> 512B-contiguous x reads and out writes.
__global__ __launch_bounds__(256, 4) void k3_gemm_ln_res(
    const unsigned short* __restrict__ tmat,
    const unsigned short* __restrict__ Wf3,
    const float* __restrict__ gamma, const float* __restrict__ beta,
    const float* __restrict__ scale,
    const float* __restrict__ x,
    float* __restrict__ out)
{
    __shared__ float bounce[4][16 * 132];   // 33.8 KB
    __shared__ float2 exch[4][16];

    const int t = threadIdx.x;
    const int lane = t & 63;
    const int wv = t >> 6;
    const int quad = lane >> 4;
    const int n16 = lane & 15;
    const int rowtile = blockIdx.x * 2 + (wv >> 1);
    const int half = wv & 1;

    const unsigned short* trow = tmat + (size_t)(rowtile * 16 + n16) * 64 + quad * 8;
    short8 a0 = *(const short8*)trow;
    short8 a1 = *(const short8*)(trow + 32);

    floatx4 acc[16];
    #pragma unroll
    for (int nt = 0; nt < 16; ++nt) acc[nt] = (floatx4){0.f, 0.f, 0.f, 0.f};
    #pragma unroll
    for (int nt = 0; nt < 16; ++nt) {
        int ngt = half * 16 + nt;
        short8 b0 = *(const short8*)&Wf3[(size_t)((ngt * 8 + quad) * 16 + n16) * 8];
        short8 b1 = *(const short8*)&Wf3[(size_t)((ngt * 8 + 4 + quad) * 16 + n16) * 8];
        acc[nt] = __builtin_amdgcn_mfma_f32_16x16x32_bf16(a0, b0, acc[nt], 0, 0, 0);
        acc[nt] = __builtin_amdgcn_mfma_f32_16x16x32_bf16(a1, b1, acc[nt], 0, 0, 0);
    }

    // Partial LN sums over this wave's 256 cols, reduce across 16 lanes.
    float s[4] = {0.f, 0.f, 0.f, 0.f}, s2[4] = {0.f, 0.f, 0.f, 0.f};
    #pragma unroll
    for (int nt = 0; nt < 16; ++nt)
        #pragma unroll
        for (int r = 0; r < 4; ++r) {
            float v = acc[nt][r];
            s[r] += v; s2[r] += v * v;
        }
    #pragma unroll
    for (int off = 1; off <= 8; off <<= 1)
        #pragma unroll
        for (int r = 0; r < 4; ++r) {
            s[r]  += __shfl_xor(s[r],  off, 64);
            s2[r] += __shfl_xor(s2[r], off, 64);
        }
    if (n16 == 0) {
        #pragma unroll
        for (int r = 0; r < 4; ++r)
            exch[wv][quad * 4 + r] = make_float2(s[r], s2[r]);
    }
    __syncthreads();
    float mean[4], rstd[4];
    #pragma unroll
    for (int r = 0; r < 4; ++r) {
        float2 o = exch[wv ^ 1][quad * 4 + r];
        float st = s[r] + o.x, st2 = s2[r] + o.y;
        mean[r] = st * (1.f / 512.f);
        float var = st2 * (1.f / 512.f) - mean[r] * mean[r];
        rstd[r] = rsqrtf(var + EPSN);
    }
    const float sc = scale[0];

    #pragma unroll
    for (int chunk = 0; chunk < 2; ++chunk) {
        __syncthreads();   // WAR vs previous chunk's reads (uniform across block)
        #pragma unroll
        for (int n0 = 0; n0 < 8; ++n0) {
            int nt = chunk * 8 + n0;
            int col = half * 256 + nt * 16 + n16;
            float gm = gamma[col], bt = beta[col];
            #pragma unroll
            for (int r = 0; r < 4; ++r)
                bounce[wv][(quad * 4 + r) * 132 + n0 * 16 + n16] =
                    sc * ((acc[nt][r] - mean[r]) * rstd[r] * gm + bt);
        }
        __syncthreads();
        #pragma unroll
        for (int pass = 0; pass < 8; ++pass) {
            int row = pass * 2 + (lane >> 5);
            int coff = (lane & 31) * 4;
            float4 v = *(const float4*)&bounce[wv][row * 132 + coff];
            size_t gidx = ((size_t)rowtile * 16 + row) * 512 + half * 256 + chunk * 128 + coff;
            float4 xv = *(const float4*)&x[gidx];
            float4 o;
            o.x = xv.x + v.x; o.y = xv.y + v.y; o.z = xv.z + v.z; o.w = xv.w + v.w;
            *(float4*)&out[gidx] = o;
        }
    }
}

extern "C" void kernel_launch(void* const* d_in, const int* in_sizes, int n_in,
                              void* d_out, int out_size, void* d_ws, size_t ws_size,
                              hipStream_t stream) {
    const float* x         = (const float*)d_in[0];
    const float* w_f       = (const float*)d_in[1];
    const float* w_h       = (const float*)d_in[2];
    const float* w_fgh     = (const float*)d_in[3];
    const float* gamma_f   = (const float*)d_in[4];
    const float* beta_f    = (const float*)d_in[5];
    const float* gamma_h   = (const float*)d_in[6];
    const float* beta_h    = (const float*)d_in[7];
    const float* gamma_fgh = (const float*)d_in[8];
    const float* beta_fgh  = (const float*)d_in[9];
    const float* scale     = (const float*)d_in[10];
    float* out = (float*)d_out;

    char* wsb = (char*)d_ws;
    float* g            = (float*)wsb;                            // 16 MB
    unsigned short* h   = (unsigned short*)(wsb + 16777216);      // 8 MB
    unsigned short* tm  = (unsigned short*)(wsb + 25165824);      // 8 MB
    unsigned short* Wgh = (unsigned short*)(wsb + 33554432);      // 128 KB
    unsigned short* Wf3 = (unsigned short*)(wsb + 33685504);      // 64 KB

    k0_convert<<<48, 256, 0, stream>>>(w_f, w_h, w_fgh, Wgh, Wf3);
    k1_gemm_ln<<<1024, 256, 0, stream>>>(x, Wgh, gamma_f, beta_f,
                                         gamma_h, beta_h, g, h);
    k2_softmax<<<1024, 256, 0, stream>>>(g, h, tm);
    k3_gemm_ln_res<<<2048, 256, 0, stream>>>(tm, Wf3, gamma_fgh, beta_fgh,
                                             scale, x, out);
}

// Round 5
// 294.674 us; speedup vs baseline: 1.1401x; 1.0086x over previous
//
#include <hip/hip_runtime.h>

#define EPSN 1e-3f

typedef __attribute__((ext_vector_type(8))) short short8;
typedef __attribute__((ext_vector_type(4))) float floatx4;

__device__ __forceinline__ unsigned f2bf_pack(float a, float b) {
    unsigned ua = __builtin_bit_cast(unsigned, a);
    ua += 0x7FFF + ((ua >> 16) & 1);
    unsigned ub = __builtin_bit_cast(unsigned, b);
    ub += 0x7FFF + ((ub >> 16) & 1);
    return (ua >> 16) | (ub & 0xFFFF0000u);
}
__device__ __forceinline__ unsigned short f2bf(float f) {
    unsigned u = __builtin_bit_cast(unsigned, f);
    u += 0x7FFF + ((u >> 16) & 1);
    return (unsigned short)(u >> 16);
}
__device__ __forceinline__ float bf2f(unsigned short u) {
    unsigned v = ((unsigned)u) << 16;
    return __builtin_bit_cast(float, v);
}

// Async global->LDS, 16B per lane: LDS dest = wave-uniform base + lane*16.
__device__ __forceinline__ void gload_lds16(const unsigned short* g, unsigned short* l) {
    __builtin_amdgcn_global_load_lds(
        (const __attribute__((address_space(1))) unsigned int*)g,
        (__attribute__((address_space(3))) unsigned int*)l,
        16, 0, 0);
}

// ---------------- Kernel 0: weights fp32 -> bf16 MFMA B-frag layout ----------
// Wgh: n in [0,128) (0..63 = w_f, 64..127 = w_h), k in [0,512).
//   Wgh[((ntile*64 + k8)*16 + n16)*8 + j] = W[k8*8+j][ntile*16+n16]
// Wf3: n in [0,512), k in [0,64).
//   Wf3[((ntile*8 + k8)*16 + n16)*8 + j] = w_fgh[k8*8+j][ntile*16+n16]
__global__ void k0_convert(const float* __restrict__ w_f,
                           const float* __restrict__ w_h,
                           const float* __restrict__ w_fgh,
                           unsigned short* __restrict__ Wgh,
                           unsigned short* __restrict__ Wf3)
{
    int tid = blockIdx.x * 256 + threadIdx.x;
    if (tid < 8192) {
        int n16 = tid & 15, k8 = (tid >> 4) & 63, ntile = tid >> 10;
        int n = ntile * 16 + n16;
        const float* src = (n < 64) ? (w_f + n) : (w_h + (n - 64));
        unsigned short o[8];
        #pragma unroll
        for (int j = 0; j < 8; ++j) o[j] = f2bf(src[(size_t)(k8 * 8 + j) * 64]);
        *(uint4*)&Wgh[(size_t)tid * 8] = *(const uint4*)o;
    } else if (tid < 12288) {
        int id = tid - 8192;
        int n16 = id & 15, k8 = (id >> 4) & 7, ntile = id >> 7;
        int n = ntile * 16 + n16;
        unsigned short o[8];
        #pragma unroll
        for (int j = 0; j < 8; ++j) o[j] = f2bf(w_fgh[(size_t)(k8 * 8 + j) * 512 + n]);
        *(uint4*)&Wf3[(size_t)id * 8] = *(const uint4*)o;
    }
}

// ---------------- Kernel 1: x @ (w_f|w_h) + fused LN -> g (fp32), h (bf16) ---
// Block 256 (4 waves), 64 rows/block, 16 rows/wave, grid 1024 (4 blocks/CU).
// B (Wgh) staged once per BLOCK into LDS via global_load_lds (double-buffered
// 16KB chunks of 2 K-steps), instead of every wave pulling all 128KB from L2:
// block-level B traffic /4, B off the vmcnt critical path (ds_read/lgkmcnt),
// freed VGPRs hold a 1-chunk x prefetch. 8 chunks, 1 barrier each.
__global__ __launch_bounds__(256, 4) void k1_gemm_ln(
    const float* __restrict__ x,
    const unsigned short* __restrict__ Wgh,
    const float* __restrict__ gamma_f, const float* __restrict__ beta_f,
    const float* __restrict__ gamma_h, const float* __restrict__ beta_h,
    float* __restrict__ g_out, unsigned short* __restrict__ h_out)
{
    __shared__ unsigned short Blds[2][8192];   // 2 x 16KB: [cl*8+ct]*512 shorts

    const int t = threadIdx.x;
    const int lane = t & 63;
    const int wv = t >> 6;
    const int quad = lane >> 4;
    const int n16 = lane & 15;
    const int row_base = blockIdx.x * 64 + wv * 16;

    floatx4 acc[8];
    #pragma unroll
    for (int ct = 0; ct < 8; ++ct) acc[ct] = (floatx4){0.f, 0.f, 0.f, 0.f};

    const float* xrow = x + (size_t)(row_base + n16) * 512 + quad * 8;
    // Global B frag (c, ct) slice base for this lane: + ct*8192 + c*512 shorts.
    const unsigned short* bsrc = Wgh + (size_t)lane * 8;

    // Stage chunk ch (K-steps 2ch, 2ch+1) into Blds[par]; wave wv owns slices
    // s = wv*4 .. wv*4+3, slice s = (cl = s>>3, ct = s&7), 1KB each.
    auto stage = [&](int par, int ch) {
        #pragma unroll
        for (int i = 0; i < 4; ++i) {
            int s = wv * 4 + i;
            int cl = s >> 3, ct = s & 7;
            gload_lds16(bsrc + (size_t)ct * 8192 + (ch * 2 + cl) * 512,
                        &Blds[par][s * 512]);
        }
    };

    stage(0, 0);
    float4 u[2], v[2];
    u[0] = *(const float4*)(xrow);
    v[0] = *(const float4*)(xrow + 4);
    u[1] = *(const float4*)(xrow + 32);
    v[1] = *(const float4*)(xrow + 36);
    __syncthreads();   // drains stage(0) (vmcnt) for all waves

    #pragma unroll
    for (int ch = 0; ch < 8; ++ch) {
        const int par = ch & 1;
        if (ch < 7) stage(par ^ 1, ch + 1);
        float4 un[2], vn[2];
        if (ch < 7) {
            un[0] = *(const float4*)(xrow + ch * 64 + 64);
            vn[0] = *(const float4*)(xrow + ch * 64 + 68);
            un[1] = *(const float4*)(xrow + ch * 64 + 96);
            vn[1] = *(const float4*)(xrow + ch * 64 + 100);
        }
        #pragma unroll
        for (int cl = 0; cl < 2; ++cl) {
            union { short8 s; uint4 q; } cvt;
            cvt.q = make_uint4(f2bf_pack(u[cl].x, u[cl].y), f2bf_pack(u[cl].z, u[cl].w),
                               f2bf_pack(v[cl].x, v[cl].y), f2bf_pack(v[cl].z, v[cl].w));
            short8 a = cvt.s;
            #pragma unroll
            for (int ct = 0; ct < 8; ++ct) {
                short8 b = *(const short8*)&Blds[par][(cl * 8 + ct) * 512 + lane * 8];
                acc[ct] = __builtin_amdgcn_mfma_f32_16x16x32_bf16(a, b, acc[ct], 0, 0, 0);
            }
        }
        if (ch < 7) {
            u[0] = un[0]; v[0] = vn[0]; u[1] = un[1]; v[1] = vn[1];
        }
        // One barrier per chunk: (a) all waves done reading Blds[par] before it
        // is restaged two chunks later, (b) stage into par^1 drained (vmcnt)
        // before next chunk reads it.
        __syncthreads();
    }

    // Epilogue: per-wave in-register LN over each 64-col half.
    #pragma unroll
    for (int half = 0; half < 2; ++half) {
        float s[4] = {0.f, 0.f, 0.f, 0.f}, s2[4] = {0.f, 0.f, 0.f, 0.f};
        #pragma unroll
        for (int c0 = 0; c0 < 4; ++c0) {
            int ct = half * 4 + c0;
            #pragma unroll
            for (int r = 0; r < 4; ++r) {
                float val = acc[ct][r];
                s[r] += val; s2[r] += val * val;
            }
        }
        #pragma unroll
        for (int off = 1; off <= 8; off <<= 1)
            #pragma unroll
            for (int r = 0; r < 4; ++r) {
                s[r]  += __shfl_xor(s[r],  off, 64);
                s2[r] += __shfl_xor(s2[r], off, 64);
            }
        float mean[4], rstd[4];
        #pragma unroll
        for (int r = 0; r < 4; ++r) {
            mean[r] = s[r] * (1.f / 64.f);
            float var = s2[r] * (1.f / 64.f) - mean[r] * mean[r];
            rstd[r] = rsqrtf(var + EPSN);
        }
        #pragma unroll
        for (int c0 = 0; c0 < 4; ++c0) {
            int ct = half * 4 + c0;
            int col = c0 * 16 + n16;
            float gm = half ? gamma_h[col] : gamma_f[col];
            float bt = half ? beta_h[col]  : beta_f[col];
            #pragma unroll
            for (int r = 0; r < 4; ++r) {
                int row = row_base + quad * 4 + r;
                float val = (acc[ct][r] - mean[r]) * rstd[r] * gm + bt;
                if (half == 0)
                    g_out[(size_t)row * 64 + col] = val;
                else
                    h_out[(size_t)row * 64 + col] = f2bf(val);
            }
        }
    }
}

// ---------------- Kernel 2: softmax over H of f*g, times h -> t (bf16 row-major)
// Rewritten: float4 staging of S only (Hm LDS dropped -> 18.5KB LDS, up to 8
// blocks/CU), h read directly from global (L3-resident) in the output pass,
// output written as 16B uint4 stores (was 2B scalar).
__global__ __launch_bounds__(256, 6) void k2_softmax(
    const float* __restrict__ g_in,
    const unsigned short* __restrict__ h_in,
    unsigned short* __restrict__ t_out)
{
    __shared__ float S[64 * 64];
    __shared__ float pmax[4 * 64];
    __shared__ float psum[4 * 64];
    __shared__ float colmax[64];
    __shared__ float colinv[64];

    const int t = threadIdx.x;
    const int b = blockIdx.x >> 6;
    const int w = blockIdx.x & 63;
    const size_t base1 = (size_t)(b * 64 + w) * 4096;

    // Stage S = f*g, vectorized: per pass, 16 lanes cover one hh-row (256B).
    #pragma unroll
    for (int p = 0; p < 4; ++p) {
        int hh = p * 16 + (t >> 4);
        int ii0 = (t & 15) * 4;
        float4 gf = *(const float4*)&g_in[base1 + hh * 64 + ii0];
        float4 gg = *(const float4*)&g_in[(size_t)((b * 64 + hh) * 64 + w) * 64 + ii0];
        float4 sv;
        sv.x = gf.x * gg.x; sv.y = gf.y * gg.y;
        sv.z = gf.z * gg.z; sv.w = gf.w * gg.w;
        *(float4*)&S[hh * 64 + ii0] = sv;
    }
    __syncthreads();

    const int q = t >> 6;
    const int i = t & 63;
    float m = -1e30f;
    #pragma unroll
    for (int r = 0; r < 16; ++r)
        m = fmaxf(m, S[(q * 16 + r) * 64 + i]);
    pmax[q * 64 + i] = m;
    __syncthreads();
    if (t < 64)
        colmax[i] = fmaxf(fmaxf(pmax[i], pmax[64 + i]),
                          fmaxf(pmax[128 + i], pmax[192 + i]));
    __syncthreads();
    const float cm = colmax[i];
    float s = 0.f;
    #pragma unroll
    for (int r = 0; r < 16; ++r) {
        int idx = (q * 16 + r) * 64 + i;
        float e = __expf(S[idx] - cm);
        S[idx] = e;
        s += e;
    }
    psum[q * 64 + i] = s;
    __syncthreads();
    if (t < 64)
        colinv[i] = 1.f / (psum[i] + psum[64 + i] + psum[128 + i] + psum[192 + i]);
    __syncthreads();

    // Output: thread t -> row hh = t>>2, 16 consecutive cols ii0 = (t&3)*16.
    // h loaded straight from global (128B contiguous per 4-lane cluster).
    {
        const int hh = t >> 2;
        const int ii0 = (t & 3) * 16;
        const size_t rowg = (size_t)((b * 64 + hh) * 64 + w) * 64;
        float4 sv[4], ci[4];
        ushort4 hv[4];
        #pragma unroll
        for (int k = 0; k < 4; ++k) {
            sv[k] = *(const float4*)&S[hh * 64 + ii0 + k * 4];
            ci[k] = *(const float4*)&colinv[ii0 + k * 4];
            hv[k] = *(const ushort4*)&h_in[rowg + ii0 + k * 4];
        }
        uint4 o0, o1;
        o0.x = f2bf_pack(sv[0].x * ci[0].x * bf2f(hv[0].x), sv[0].y * ci[0].y * bf2f(hv[0].y));
        o0.y = f2bf_pack(sv[0].z * ci[0].z * bf2f(hv[0].z), sv[0].w * ci[0].w * bf2f(hv[0].w));
        o0.z = f2bf_pack(sv[1].x * ci[1].x * bf2f(hv[1].x), sv[1].y * ci[1].y * bf2f(hv[1].y));
        o0.w = f2bf_pack(sv[1].z * ci[1].z * bf2f(hv[1].z), sv[1].w * ci[1].w * bf2f(hv[1].w));
        o1.x = f2bf_pack(sv[2].x * ci[2].x * bf2f(hv[2].x), sv[2].y * ci[2].y * bf2f(hv[2].y));
        o1.y = f2bf_pack(sv[2].z * ci[2].z * bf2f(hv[2].z), sv[2].w * ci[2].w * bf2f(hv[2].w));
        o1.z = f2bf_pack(sv[3].x * ci[3].x * bf2f(hv[3].x), sv[3].y * ci[3].y * bf2f(hv[3].y));
        o1.w = f2bf_pack(sv[3].z * ci[3].z * bf2f(hv[3].z), sv[3].w * ci[3].w * bf2f(hv[3].w));
        *(uint4*)&t_out[rowg + ii0] = o0;
        *(uint4*)&t_out[rowg + ii0 + 8] = o1;
    }
}

// ---------------- Kernel 3: t @ w_fgh + LN + scale + residual ----------------
// Block 256 (4 waves): 2 rowtiles x 2 col-halves (256 cols/wave). B-frags from
// global Wf3. Cross-wave LN pairing via tiny LDS. Epilogue via per-wave 8KB
// bounce -> 512B-contiguous x reads and out writes.
__global__ __launch_bounds__(256, 4) void k3_gemm_ln_res(
    const unsigned short* __restrict__ tmat,
    const unsigned short* __restrict__ Wf3,
    const float* __restrict__ gamma, const float* __restrict__ beta,
    const float* __restrict__ scale,
    const float* __restrict__ x,
    float* __restrict__ out)
{
    __shared__ float bounce[4][16 * 132];   // 33.8 KB
    __shared__ float2 exch[4][16];

    const int t = threadIdx.x;
    const int lane = t & 63;
    const int wv = t >> 6;
    const int quad = lane >> 4;
    const int n16 = lane & 15;
    const int rowtile = blockIdx.x * 2 + (wv >> 1);
    const int half = wv & 1;

    const unsigned short* trow = tmat + (size_t)(rowtile * 16 + n16) * 64 + quad * 8;
    short8 a0 = *(const short8*)trow;
    short8 a1 = *(const short8*)(trow + 32);

    floatx4 acc[16];
    #pragma unroll
    for (int nt = 0; nt < 16; ++nt) acc[nt] = (floatx4){0.f, 0.f, 0.f, 0.f};
    #pragma unroll
    for (int nt = 0; nt < 16; ++nt) {
        int ngt = half * 16 + nt;
        short8 b0 = *(const short8*)&Wf3[(size_t)((ngt * 8 + quad) * 16 + n16) * 8];
        short8 b1 = *(const short8*)&Wf3[(size_t)((ngt * 8 + 4 + quad) * 16 + n16) * 8];
        acc[nt] = __builtin_amdgcn_mfma_f32_16x16x32_bf16(a0, b0, acc[nt], 0, 0, 0);
        acc[nt] = __builtin_amdgcn_mfma_f32_16x16x32_bf16(a1, b1, acc[nt], 0, 0, 0);
    }

    // Partial LN sums over this wave's 256 cols, reduce across 16 lanes.
    float s[4] = {0.f, 0.f, 0.f, 0.f}, s2[4] = {0.f, 0.f, 0.f, 0.f};
    #pragma unroll
    for (int nt = 0; nt < 16; ++nt)
        #pragma unroll
        for (int r = 0; r < 4; ++r) {
            float v = acc[nt][r];
            s[r] += v; s2[r] += v * v;
        }
    #pragma unroll
    for (int off = 1; off <= 8; off <<= 1)
        #pragma unroll
        for (int r = 0; r < 4; ++r) {
            s[r]  += __shfl_xor(s[r],  off, 64);
            s2[r] += __shfl_xor(s2[r], off, 64);
        }
    if (n16 == 0) {
        #pragma unroll
        for (int r = 0; r < 4; ++r)
            exch[wv][quad * 4 + r] = make_float2(s[r], s2[r]);
    }
    __syncthreads();
    float mean[4], rstd[4];
    #pragma unroll
    for (int r = 0; r < 4; ++r) {
        float2 o = exch[wv ^ 1][quad * 4 + r];
        float st = s[r] + o.x, st2 = s2[r] + o.y;
        mean[r] = st * (1.f / 512.f);
        float var = st2 * (1.f / 512.f) - mean[r] * mean[r];
        rstd[r] = rsqrtf(var + EPSN);
    }
    const float sc = scale[0];

    #pragma unroll
    for (int chunk = 0; chunk < 2; ++chunk) {
        __syncthreads();   // WAR vs previous chunk's reads (uniform across block)
        #pragma unroll
        for (int n0 = 0; n0 < 8; ++n0) {
            int nt = chunk * 8 + n0;
            int col = half * 256 + nt * 16 + n16;
            float gm = gamma[col], bt = beta[col];
            #pragma unroll
            for (int r = 0; r < 4; ++r)
                bounce[wv][(quad * 4 + r) * 132 + n0 * 16 + n16] =
                    sc * ((acc[nt][r] - mean[r]) * rstd[r] * gm + bt);
        }
        __syncthreads();
        #pragma unroll
        for (int pass = 0; pass < 8; ++pass) {
            int row = pass * 2 + (lane >> 5);
            int coff = (lane & 31) * 4;
            float4 v = *(const float4*)&bounce[wv][row * 132 + coff];
            size_t gidx = ((size_t)rowtile * 16 + row) * 512 + half * 256 + chunk * 128 + coff;
            float4 xv = *(const float4*)&x[gidx];
            float4 o;
            o.x = xv.x + v.x; o.y = xv.y + v.y; o.z = xv.z + v.z; o.w = xv.w + v.w;
            *(float4*)&out[gidx] = o;
        }
    }
}

extern "C" void kernel_launch(void* const* d_in, const int* in_sizes, int n_in,
                              void* d_out, int out_size, void* d_ws, size_t ws_size,
                              hipStream_t stream) {
    const float* x         = (const float*)d_in[0];
    const float* w_f       = (const float*)d_in[1];
    const float* w_h       = (const float*)d_in[2];
    const float* w_fgh     = (const float*)d_in[3];
    const float* gamma_f   = (const float*)d_in[4];
    const float* beta_f    = (const float*)d_in[5];
    const float* gamma_h   = (const float*)d_in[6];
    const float* beta_h    = (const float*)d_in[7];
    const float* gamma_fgh = (const float*)d_in[8];
    const float* beta_fgh  = (const float*)d_in[9];
    const float* scale     = (const float*)d_in[10];
    float* out = (float*)d_out;

    char* wsb = (char*)d_ws;
    float* g            = (float*)wsb;                            // 16 MB
    unsigned short* h   = (unsigned short*)(wsb + 16777216);      // 8 MB
    unsigned short* tm  = (unsigned short*)(wsb + 25165824);      // 8 MB
    unsigned short* Wgh = (unsigned short*)(wsb + 33554432);      // 128 KB
    unsigned short* Wf3 = (unsigned short*)(wsb + 33685504);      // 64 KB

    k0_convert<<<48, 256, 0, stream>>>(w_f, w_h, w_fgh, Wgh, Wf3);
    k1_gemm_ln<<<1024, 256, 0, stream>>>(x, Wgh, gamma_f, beta_f,
                                         gamma_h, beta_h, g, h);
    k2_softmax<<<1024, 256, 0, stream>>>(g, h, tm);
    k3_gemm_ln_res<<<2048, 256, 0, stream>>>(tm, Wf3, gamma_fgh, beta_fgh,
                                             scale, x, out);
}